// Round 9
// baseline (598.182 us; speedup 1.0000x reference)
//
#include <hip/hip_runtime.h>
#include <cstdint>
#include <cstddef>

// ---------------------------------------------------------------------------
// SelfModifyingRecurrent: B=8192, E=1024, L=3
//   * h_prev stays ZERO -> gh = b_hh (const), no W_hh GEMM
//   * weight modification is rank-1 -> gi += cond * 0.01*dot(cur, mean_sig)
// R7 analysis: all GEMMs sit at the 2-phase-structure stall ceiling (~620 TF);
// FETCH halved with no time change -> stall-bound, not traffic-bound.
// This round: FUSE act0-GEMM + gru-GEMM (same A, same K, gru GEMM doesn't
// need sig) into gemm_big (NG=4, 64 MFMA/wave/K-step) writing Amat + gi(f16,
// bih folded); GRU cell moves to a BW-bound elementwise gru_finish kernel.
// act1 widened to NG=2. Per-layer CU-serialized K-steps: ~48 -> ~28.
// ---------------------------------------------------------------------------

#define BSZ 8192
#define ESZ 1024

typedef _Float16 f16x8 __attribute__((ext_vector_type(8)));
typedef float    f32x4 __attribute__((ext_vector_type(4)));
typedef unsigned short u16;
typedef u16 u16x4 __attribute__((ext_vector_type(4)));

__device__ __forceinline__ u16 f2h(float f) {
    _Float16 h = (_Float16)f;
    return __builtin_bit_cast(u16, h);
}
__device__ __forceinline__ float h2f(u16 h) {
    return (float)__builtin_bit_cast(_Float16, h);
}

__device__ __forceinline__ void gload16(const void* g, void* l) {
    __builtin_amdgcn_global_load_lds((const __attribute__((address_space(1))) void*)g,
                                     (__attribute__((address_space(3))) void*)l,
                                     16, 0, 0);
}

// swizzled LDS u16 index: row-stride 64 u16 (128B), chunk = 8-u16 (16B) slot 0..7
__device__ __forceinline__ int swzi(int row, int chunk) {
    return (row << 6) + (((chunk ^ row) & 7) << 3);
}

__device__ __forceinline__ float sigmoidf_(float x) {
    return 1.f / (1.f + __expf(-x));
}
__device__ __forceinline__ float tanhf_(float x) {
    float cx = fminf(fmaxf(x, -15.f), 15.f);
    float e = __expf(2.f * cx);
    return (e - 1.f) / (e + 1.f);
}

// ---------------------------------------------------------------------------
// fused fp32 -> f16 conversion for Wih, W1, W2, x (one launch)
// ---------------------------------------------------------------------------
#define N4_WIH (3 * 3072 * 1024 / 4)
#define N4_W1  (3 * 512 * 1024 / 4)
#define N4_W2  (3 * 1024 * 512 / 4)
#define N4_X   (BSZ * ESZ / 4)

__global__ void cvt_all_kernel(const float* __restrict__ Wih, const float* __restrict__ W1,
                               const float* __restrict__ W2, const float* __restrict__ x,
                               u16* __restrict__ oWih, u16* __restrict__ oW1,
                               u16* __restrict__ oW2, u16* __restrict__ ox) {
    int i = blockIdx.x * 256 + threadIdx.x;
    const float* in;
    u16* out;
    if (i < N4_WIH) { in = Wih; out = oWih; }
    else if (i < N4_WIH + N4_W1) { i -= N4_WIH; in = W1; out = oW1; }
    else if (i < N4_WIH + N4_W1 + N4_W2) { i -= N4_WIH + N4_W1; in = W2; out = oW2; }
    else { i -= N4_WIH + N4_W1 + N4_W2; if (i >= N4_X) return; in = x; out = ox; }
    f32x4 v = ((const f32x4*)in)[i];
    u16x4 o;
    o.x = f2h(v.x); o.y = f2h(v.y); o.z = f2h(v.z); o.w = f2h(v.w);
    ((u16x4*)out)[i] = o;
}

// ---------------------------------------------------------------------------
// Gate kernel (reads f16 cur): per row r:
//   gate_r = sigmoid(dot(cur_r, Wg) + bg)       -> atomic sum into gsum
//   sdot_r = dot(cur_r, colsum_sig)*(0.01/B)
// ---------------------------------------------------------------------------
__global__ void gate_kernel(const u16* __restrict__ cur, const float* __restrict__ Wg,
                            const float* __restrict__ bg, const float* __restrict__ colsum,
                            float* __restrict__ gsum, float* __restrict__ sdot) {
    const int wid = threadIdx.x >> 6, lane = threadIdx.x & 63;
    const int row = blockIdx.x * 4 + wid;
    const u16* cr = cur + (size_t)row * ESZ;
    float pg = 0.f, pm = 0.f;
#pragma unroll
    for (int h = 0; h < 2; h++) {
        int base = lane * 16 + h * 8;
        f16x8 cv = *(const f16x8*)(cr + base);
#pragma unroll
        for (int q = 0; q < 2; q++) {
            f32x4 wv = *(const f32x4*)(Wg + base + q * 4);
            f32x4 mv = *(const f32x4*)(colsum + base + q * 4);
#pragma unroll
            for (int e = 0; e < 4; e++) {
                float c = (float)cv[q * 4 + e];
                pg += c * wv[e];
                pm += c * mv[e];
            }
        }
    }
#pragma unroll
    for (int s = 32; s >= 1; s >>= 1) {
        pg += __shfl_xor(pg, s);
        pm += __shfl_xor(pm, s);
    }
    __shared__ float gp[4];
    if (lane == 0) {
        gp[wid] = sigmoidf_(pg + bg[0]);
        sdot[row] = pm * (0.01f / 8192.f);
    }
    __syncthreads();
    if (threadIdx.x == 0) atomicAdd(gsum, gp[0] + gp[1] + gp[2] + gp[3]);
}

// ---------------------------------------------------------------------------
// gemm_big: fused act0 + gru-GEMM. A = cur [8192 x 1024] staged ONCE.
// Combined column space: 56 groups of 64 = 8 (W1 -> relu -> Amat) + 48
// (W_ih -> +bih -> gi f16). Block: 256 rows x 4 groups; 8 waves (4M x 2N);
// BK=64, 2-phase dbuf, XOR-swizzled staging. Grid 448 = 8 XCD x (4 panels x
// 14 col-chunks); A panel chunk (2MB) L2-resident per XCD.
// ---------------------------------------------------------------------------
__global__ void __launch_bounds__(512, 2) gemm_big_kernel(
    const u16* __restrict__ A, const u16* __restrict__ W1l, const u16* __restrict__ Wihl,
    const float* __restrict__ b1l, const float* __restrict__ bihl,
    u16* __restrict__ Amat, u16* __restrict__ gi) {
    __shared__ u16 lA[2][256 * 64];
    __shared__ u16 lB[2][4][64 * 64];
    const int t = threadIdx.x;
    const int xcd = blockIdx.x & 7, q = blockIdx.x >> 3;  // q: 0..55
    const int m0 = (xcd * 4 + (q & 3)) * 256;             // 4 contiguous panels/XCD
    const int cb = q >> 2;                                // col-chunk 0..13 (outer)
    const int wid = t >> 6, lane = t & 63;
    const int waver = wid >> 1, wavec = wid & 1;
    const int lrow = lane & 15, lk = lane >> 4;
    const int K = 1024;

    f32x4 acc[4][8] = {};

    auto STAGE = [&](int buf, int k0) {
#pragma unroll
        for (int i = 0; i < 4; i++) {
            int eo = i * 4096 + t * 8;
            int r = eo >> 6;
            int gc = (((eo >> 3) ^ r) & 7) << 3;
            gload16(A + (size_t)(m0 + r) * K + k0 + gc, &lA[buf][eo]);
        }
#pragma unroll
        for (int g = 0; g < 4; g++) {
            int cg = cb * 4 + g;
            const u16* Wp = (cg < 8) ? (W1l + (size_t)cg * 64 * K)
                                     : (Wihl + (size_t)(cg - 8) * 64 * K);
            int eo = t * 8;
            int r = eo >> 6;
            int gc = (((eo >> 3) ^ r) & 7) << 3;
            gload16(Wp + (size_t)r * K + k0 + gc, &lB[buf][g][eo]);
        }
    };

    STAGE(0, 0);
    int cur = 0;
    for (int kt = 0; kt < 16; ++kt) {
        __syncthreads();
        if (kt < 15) STAGE(cur ^ 1, (kt + 1) * 64);
#pragma unroll
        for (int kk = 0; kk < 2; kk++) {
            f16x8 af[4];
#pragma unroll
            for (int m = 0; m < 4; m++)
                af[m] = *(const f16x8*)&lA[cur][swzi(waver * 64 + m * 16 + lrow, kk * 4 + lk)];
#pragma unroll
            for (int g = 0; g < 4; g++) {
#pragma unroll
                for (int n = 0; n < 2; n++) {
                    f16x8 bf = *(const f16x8*)&lB[cur][g][swzi(wavec * 32 + n * 16 + lrow, kk * 4 + lk)];
#pragma unroll
                    for (int m = 0; m < 4; m++)
                        acc[m][g * 2 + n] =
                            __builtin_amdgcn_mfma_f32_16x16x32_f16(af[m], bf, acc[m][g * 2 + n], 0, 0, 0);
                }
            }
        }
        cur ^= 1;
    }

#pragma unroll
    for (int g = 0; g < 4; g++) {
        int cg = cb * 4 + g;
#pragma unroll
        for (int n = 0; n < 2; n++) {
            int cl = wavec * 32 + n * 16 + lrow;
            if (cg < 8) {                                  // act0: relu -> Amat
                int c = cg * 64 + cl;
                float bv = b1l[c];
#pragma unroll
                for (int m = 0; m < 4; m++) {
                    int rbase = m0 + waver * 64 + m * 16 + lk * 4;
#pragma unroll
                    for (int j = 0; j < 4; j++) {
                        float v = acc[m][g * 2 + n][j] + bv;
                        Amat[(size_t)(rbase + j) * 512 + c] = f2h(v > 0.f ? v : 0.f);
                    }
                }
            } else {                                       // gru GEMM: +bih -> gi
                int c = (cg - 8) * 64 + cl;
                float bv = bihl[c];
#pragma unroll
                for (int m = 0; m < 4; m++) {
                    int rbase = m0 + waver * 64 + m * 16 + lk * 4;
#pragma unroll
                    for (int j = 0; j < 4; j++)
                        gi[(size_t)(rbase + j) * 3072 + c] = f2h(acc[m][g * 2 + n][j] + bv);
                }
            }
        }
    }
}

// ---------------------------------------------------------------------------
// act1: sig = tanh(Amat @ W2^T + b2) (f16) + fp32 column sums.
// Block: 256 rows x 128 cols (NG=2); K=512 (8 K-steps); grid 256 = 8 x (4x8).
// ---------------------------------------------------------------------------
__global__ void __launch_bounds__(512, 2) gemm_act1_kernel(
    const u16* __restrict__ A, const u16* __restrict__ W,
    const float* __restrict__ bias, u16* __restrict__ outp,
    float* __restrict__ colsum) {
    __shared__ u16 lA[2][256 * 64];
    __shared__ u16 lB[2][2][64 * 64];
    const int t = threadIdx.x;
    const int xcd = blockIdx.x & 7, q = blockIdx.x >> 3;  // q: 0..31
    const int m0 = (xcd * 4 + (q & 3)) * 256;
    const int c0 = (q >> 2) * 128;
    const int wid = t >> 6, lane = t & 63;
    const int waver = wid >> 1, wavec = wid & 1;
    const int lrow = lane & 15, lk = lane >> 4;
    const int K = 512;

    f32x4 acc[4][4] = {};

    auto STAGE = [&](int buf, int k0) {
#pragma unroll
        for (int i = 0; i < 4; i++) {
            int eo = i * 4096 + t * 8;
            int r = eo >> 6;
            int gc = (((eo >> 3) ^ r) & 7) << 3;
            gload16(A + (size_t)(m0 + r) * K + k0 + gc, &lA[buf][eo]);
        }
#pragma unroll
        for (int g = 0; g < 2; g++) {
            int eo = t * 8;
            int r = eo >> 6;
            int gc = (((eo >> 3) ^ r) & 7) << 3;
            gload16(W + (size_t)(c0 + g * 64 + r) * K + k0 + gc, &lB[buf][g][eo]);
        }
    };

    STAGE(0, 0);
    int cur = 0;
    for (int kt = 0; kt < 8; ++kt) {
        __syncthreads();
        if (kt < 7) STAGE(cur ^ 1, (kt + 1) * 64);
#pragma unroll
        for (int kk = 0; kk < 2; kk++) {
            f16x8 af[4];
#pragma unroll
            for (int m = 0; m < 4; m++)
                af[m] = *(const f16x8*)&lA[cur][swzi(waver * 64 + m * 16 + lrow, kk * 4 + lk)];
#pragma unroll
            for (int g = 0; g < 2; g++) {
#pragma unroll
                for (int n = 0; n < 2; n++) {
                    f16x8 bf = *(const f16x8*)&lB[cur][g][swzi(wavec * 32 + n * 16 + lrow, kk * 4 + lk)];
#pragma unroll
                    for (int m = 0; m < 4; m++)
                        acc[m][g * 2 + n] =
                            __builtin_amdgcn_mfma_f32_16x16x32_f16(af[m], bf, acc[m][g * 2 + n], 0, 0, 0);
                }
            }
        }
        cur ^= 1;
    }

#pragma unroll
    for (int g = 0; g < 2; g++) {
#pragma unroll
        for (int n = 0; n < 2; n++) {
            int c = c0 + g * 64 + wavec * 32 + n * 16 + lrow;
            float bv = bias[c];
            float cs = 0.f;
#pragma unroll
            for (int m = 0; m < 4; m++) {
                int rbase = m0 + waver * 64 + m * 16 + lk * 4;
#pragma unroll
                for (int j = 0; j < 4; j++) {
                    float tv = tanhf_(acc[m][g * 2 + n][j] + bv);
                    outp[(size_t)(rbase + j) * 1024 + c] = f2h(tv);
                    cs += tv;
                }
            }
            cs += __shfl_xor(cs, 16);
            cs += __shfl_xor(cs, 32);
            if (lane < 16) atomicAdd(&colsum[c], cs);
        }
    }
}

// ---------------------------------------------------------------------------
// gru_finish: elementwise GRU cell (h_prev=0) + rank-1 corr + sig add.
//   gi already contains cur@W_ih^T + b_ih (f16). 8 elems/thread.
//   r = sig(ir+corr+bhh_r); z = sig(iz+corr+bhh_z); n = tanh(in+corr+r*bhh_n)
//   out = (1-z)*n + sig_mlp
// ---------------------------------------------------------------------------
__global__ void gru_finish_kernel(const u16* __restrict__ gi, const u16* __restrict__ sig,
                                  const float* __restrict__ bhh, const float* __restrict__ sdot,
                                  const float* __restrict__ gsum, float* __restrict__ curf,
                                  u16* __restrict__ curb) {
    const int i = blockIdx.x * 256 + threadIdx.x;   // chunk of 8, total B*E/8
    const int row = i >> 7;                         // E/8 = 128 chunks per row
    const int cc = (i & 127) * 8;
    const u16* gr = gi + (size_t)row * 3072;
    f16x8 vr = *(const f16x8*)(gr + cc);
    f16x8 vz = *(const f16x8*)(gr + 1024 + cc);
    f16x8 vn = *(const f16x8*)(gr + 2048 + cc);
    f16x8 vs = *(const f16x8*)(sig + (size_t)row * 1024 + cc);
    const float corr = (*gsum > 4096.f) ? sdot[row] : 0.f;
    float o[8];
#pragma unroll
    for (int j = 0; j < 8; j++) {
        float hr = bhh[cc + j], hz = bhh[1024 + cc + j], hn = bhh[2048 + cc + j];
        float r = sigmoidf_((float)vr[j] + corr + hr);
        float z = sigmoidf_((float)vz[j] + corr + hz);
        float n = tanhf_((float)vn[j] + corr + r * hn);
        o[j] = (1.f - z) * n + (float)vs[j];
    }
    if (curb) {
        f16x8 ov;
#pragma unroll
        for (int j = 0; j < 8; j++) ov[j] = (_Float16)o[j];
        *(f16x8*)(curb + (size_t)row * 1024 + cc) = ov;
    }
    if (curf) {
        float* dst = curf + (size_t)row * 1024 + cc;
#pragma unroll
        for (int j = 0; j < 8; j++) dst[j] = o[j];
    }
}

// ---------------------------------------------------------------------------
extern "C" void kernel_launch(void* const* d_in, const int* in_sizes, int n_in,
                              void* d_out, int out_size, void* d_ws, size_t ws_size,
                              hipStream_t stream) {
    const float* x   = (const float*)d_in[0];
    const float* Wih = (const float*)d_in[1];
    // d_in[2] = W_hh : unused (h_prev == 0)
    const float* bih = (const float*)d_in[3];
    const float* bhh = (const float*)d_in[4];
    const float* W1  = (const float*)d_in[5];
    const float* b1  = (const float*)d_in[6];
    const float* W2  = (const float*)d_in[7];
    const float* b2  = (const float*)d_in[8];
    const float* Wg  = (const float*)d_in[9];
    const float* bg  = (const float*)d_in[10];
    float* out = (float*)d_out;

    char* w = (char*)d_ws;
    u16* Wihb  = (u16*)w;  w += (size_t)3 * 3072 * 1024 * 2;   // 18.9 MB
    u16* W1b   = (u16*)w;  w += (size_t)3 * 512 * 1024 * 2;    //  3.1 MB
    u16* W2b   = (u16*)w;  w += (size_t)3 * 1024 * 512 * 2;    //  3.1 MB
    u16* curbA = (u16*)w;  w += (size_t)BSZ * ESZ * 2;         // 16.8 MB
    u16* curbB = (u16*)w;  w += (size_t)BSZ * ESZ * 2;         // 16.8 MB
    u16* Amat  = (u16*)w;  w += (size_t)BSZ * 512 * 2;         //  8.4 MB
    u16* sigb  = (u16*)w;  w += (size_t)BSZ * ESZ * 2;         // 16.8 MB
    u16* gib   = (u16*)w;  w += (size_t)BSZ * 3072 * 2;        // 50.3 MB
    float* colsum = (float*)w;  w += 4096;                     // 1024 f32
    float* gsum   = (float*)w;  w += 256;                      // 1 f32 (+pad)
    float* sdot   = (float*)w;  w += (size_t)BSZ * 4;          // 32 KB

    // f16 conversions (every call — no persistent state allowed)
    {
        int n4 = N4_WIH + N4_W1 + N4_W2 + N4_X;
        cvt_all_kernel<<<dim3((n4 + 255) / 256), 256, 0, stream>>>(
            Wih, W1, W2, x, Wihb, W1b, W2b, curbA);
    }

    u16* cin = curbA;
    u16* cout = curbB;
    for (int l = 0; l < 3; l++) {
        hipMemsetAsync(colsum, 0, 4096 + 4, stream);  // colsum + gsum
        // fused: Amat = relu(cur@W1^T+b1); gi = cur@W_ih^T + b_ih (f16)
        gemm_big_kernel<<<dim3(448), 512, 0, stream>>>(
            cin, W1b + (size_t)l * 512 * 1024, Wihb + (size_t)l * 3072 * 1024,
            b1 + l * 512, bih + l * 3072, Amat, gib);
        // sig = tanh(Amat@W2^T+b2) (f16) + fp32 column sums
        gemm_act1_kernel<<<dim3(256), 512, 0, stream>>>(
            Amat, W2b + (size_t)l * 1024 * 512, b2 + l * 1024, sigb, colsum);
        // gate mean (-> cond) and rank-1 row dots
        gate_kernel<<<dim3(BSZ / 4), 256, 0, stream>>>(
            cin, Wg + l * 1024, bg + l, colsum, gsum, sdot);
        // elementwise GRU cell + sig add
        gru_finish_kernel<<<dim3(BSZ * ESZ / 8 / 256), 256, 0, stream>>>(
            gib, sigb, bhh + l * 3072, sdot, gsum,
            (l == 2) ? out : nullptr, (l < 2) ? cout : nullptr);
        u16* tmp = cin; cin = cout; cout = tmp;
    }
}